// Round 4
// baseline (251.794 us; speedup 1.0000x reference)
//
#include <hip/hip_runtime.h>
#include <stdint.h>

// AffineCoupling: B=65536 rows, DIM=128, D_IN=64, HID=512, 2 extra hidden layers.
// Fused bf16-MFMA. 128 rows/block (512 blocks), 8 waves; each wave owns
// 64 neurons x 128 rows (4x8 16x16x32 frags): 4 A-frag global + 8 B-frag LDS
// reads feed 32 MFMAs per K=32 step. h in LDS with stride 1040B (65x16):
// bank = (4*(l15+lq)+d) mod 32 -> perfectly uniform, zero conflicts, and
// addresses linear in k (ds_read immediate offsets, no VALU in loop).
// K-loop ping-pongs BOTH A and B fragments one step ahead; setprio(1) wraps
// each MFMA cluster. log_s stashed in out's z2 region (same-thread RAW).

#define NROWS 65536
#define RPB   128
#define NBLK  (NROWS / RPB)
#define HSTR  1040           // LDS row stride in bytes (65 x 16B)

// bf16 weight scratch layout (element offsets in d_ws)
#define OFF_S_WIN   0
#define OFF_S_WHID  32768
#define OFF_S_WOUT  557056
#define OFF_T_WIN   589824
#define OFF_T_WHID  622592
#define OFF_T_WOUT  1146880
#define W_ELEMS     1179648

typedef __attribute__((ext_vector_type(8))) short short8;
typedef __attribute__((ext_vector_type(4))) float f32x4;

__device__ __forceinline__ uint32_t f2bf1(float f) {
  uint32_t u = __float_as_uint(f);
  return (u + 0x7fffu + ((u >> 16) & 1u)) >> 16;   // RNE
}
__device__ __forceinline__ uint32_t pk2bf(float a, float b) {
  return f2bf1(a) | (f2bf1(b) << 16);
}

// ---------------- weight fp32 -> bf16 prologue ----------------
__global__ void cvt_weights(const float* __restrict__ sWin, const float* __restrict__ sWhid,
                            const float* __restrict__ sWout, const float* __restrict__ tWin,
                            const float* __restrict__ tWhid, const float* __restrict__ tWout,
                            uint16_t* __restrict__ wbf) {
  int g = blockIdx.x * blockDim.x + threadIdx.x;
  int e = g * 4;
  if (e >= W_ELEMS) return;
  const float* src; int off;
  if      (e < OFF_S_WHID) { src = sWin;  off = e; }
  else if (e < OFF_S_WOUT) { src = sWhid; off = e - OFF_S_WHID; }
  else if (e < OFF_T_WIN)  { src = sWout; off = e - OFF_S_WOUT; }
  else if (e < OFF_T_WHID) { src = tWin;  off = e - OFF_T_WIN; }
  else if (e < OFF_T_WOUT) { src = tWhid; off = e - OFF_T_WHID; }
  else                     { src = tWout; off = e - OFF_T_WOUT; }
  f32x4 v = *(const f32x4*)(src + off);
  uint2 r; r.x = pk2bf(v.x, v.y); r.y = pk2bf(v.z, v.w);
  *(uint2*)(wbf + e) = r;
}

// ---------------- fragment loaders ----------------
// A-frag (weights, row-major [M][K]): lane l supplies W[m=base+(l&15)][k=(l>>4)*8+j]
template<bool BF>
__device__ __forceinline__ short8 ldW(const uint16_t* __restrict__ wb,
                                      const float* __restrict__ wf, int idx) {
  if (BF) {
    return *(const short8*)(wb + idx);
  } else {  // fallback: convert fp32 weights on the fly
    f32x4 x = *(const f32x4*)(wf + idx);
    f32x4 y = *(const f32x4*)(wf + idx + 4);
    short8 r;
    r[0] = (short)f2bf1(x.x); r[1] = (short)f2bf1(x.y);
    r[2] = (short)f2bf1(x.z); r[3] = (short)f2bf1(x.w);
    r[4] = (short)f2bf1(y.x); r[5] = (short)f2bf1(y.y);
    r[6] = (short)f2bf1(y.z); r[7] = (short)f2bf1(y.w);
    return r;
  }
}

// B-frag (activations h^T from LDS, padded stride HSTR): linear addressing.
__device__ __forceinline__ short8 ldsB(const uint16_t* buf, int row, int k) {
  return *(const short8*)((const char*)buf + row * HSTR + k * 2);
}

// ---------------- epilogue: bias + relu + pack + padded LDS store ----------------
__device__ __forceinline__ void store_h(f32x4 acc[4][8], const float* __restrict__ bias,
                                        uint16_t* hdst, int wave, int lane) {
  const int l15 = lane & 15, lq = lane >> 4;
  __syncthreads();   // all waves done READING h (h is read+written in place)
  #pragma unroll
  for (int rt = 0; rt < 4; ++rt) {
    const int n0 = wave * 64 + rt * 16 + lq * 4;
    f32x4 bv = *(const f32x4*)(bias + n0);
    #pragma unroll
    for (int ct = 0; ct < 8; ++ct) {
      const int row = ct * 16 + l15;
      f32x4 v = acc[rt][ct] + bv;
      uint2 p;
      p.x = pk2bf(fmaxf(v.x, 0.f), fmaxf(v.y, 0.f));
      p.y = pk2bf(fmaxf(v.z, 0.f), fmaxf(v.w, 0.f));
      *(uint2*)((char*)hdst + row * HSTR + n0 * 2) = p;
    }
  }
  __syncthreads();
}

// ---------------- layer 1: h = relu(W @ z1^T + b), K=64, B built from global z ----------------
template<bool BF>
__device__ __forceinline__ void dense_in(
    const uint16_t* __restrict__ wb, const float* __restrict__ wf,
    const float* __restrict__ bias, const float* __restrict__ z, long rowbase,
    uint16_t* hdst, int wave, int lane) {
  const int l15 = lane & 15, lq = lane >> 4;
  f32x4 acc[4][8];
  #pragma unroll
  for (int rt = 0; rt < 4; ++rt)
    #pragma unroll
    for (int ct = 0; ct < 8; ++ct) acc[rt][ct] = (f32x4){0.f, 0.f, 0.f, 0.f};
  const int wbase = (wave * 64 + l15) * 64 + lq * 8;
  #pragma unroll
  for (int k0 = 0; k0 < 64; k0 += 32) {
    short8 a[4];
    #pragma unroll
    for (int rt = 0; rt < 4; ++rt) a[rt] = ldW<BF>(wb, wf, wbase + rt * 1024 + k0);
    #pragma unroll
    for (int ct = 0; ct < 8; ++ct) {
      const float* zp = z + (rowbase + ct * 16 + l15) * 128 + lq * 8 + k0;
      f32x4 u = *(const f32x4*)zp;
      f32x4 v = *(const f32x4*)(zp + 4);
      short8 b;
      b[0] = (short)f2bf1(u.x); b[1] = (short)f2bf1(u.y);
      b[2] = (short)f2bf1(u.z); b[3] = (short)f2bf1(u.w);
      b[4] = (short)f2bf1(v.x); b[5] = (short)f2bf1(v.y);
      b[6] = (short)f2bf1(v.z); b[7] = (short)f2bf1(v.w);
      #pragma unroll
      for (int rt = 0; rt < 4; ++rt)
        acc[rt][ct] = __builtin_amdgcn_mfma_f32_16x16x32_bf16(a[rt], b, acc[rt][ct], 0, 0, 0);
    }
  }
  store_h(acc, bias, hdst, wave, lane);
}

// ---------------- hidden layer: h = relu(W @ h^T + b), K=512 ----------------
// Ping-pong software pipeline: A and B fragments for step k+1 issued while
// MFMA cluster for step k runs. All LDS addresses are base + imm offset.
template<bool BF>
__device__ __forceinline__ void dense_relu512(
    const uint16_t* __restrict__ wb, const float* __restrict__ wf,
    const float* __restrict__ bias, uint16_t* hbuf, int wave, int lane) {
  const int l15 = lane & 15, lq = lane >> 4;
  f32x4 acc[4][8];
  #pragma unroll
  for (int rt = 0; rt < 4; ++rt)
    #pragma unroll
    for (int ct = 0; ct < 8; ++ct) acc[rt][ct] = (f32x4){0.f, 0.f, 0.f, 0.f};
  const int wbase = (wave * 64 + l15) * 512 + lq * 8;
  const char* bbase = (const char*)hbuf + l15 * HSTR + lq * 16;

  short8 a0[4], a1[4], b0[8], b1[8];
  #pragma unroll
  for (int rt = 0; rt < 4; ++rt) a0[rt] = ldW<BF>(wb, wf, wbase + rt * 8192);
  #pragma unroll
  for (int ct = 0; ct < 8; ++ct) b0[ct] = *(const short8*)(bbase + ct * 16 * HSTR);

  #pragma unroll 1
  for (int k0 = 0; k0 < 512; k0 += 64) {
    // prefetch k0+32 (always in range: k0+32 <= 480)
    #pragma unroll
    for (int rt = 0; rt < 4; ++rt) a1[rt] = ldW<BF>(wb, wf, wbase + rt * 8192 + k0 + 32);
    #pragma unroll
    for (int ct = 0; ct < 8; ++ct)
      b1[ct] = *(const short8*)(bbase + ct * 16 * HSTR + (k0 + 32) * 2);
    __builtin_amdgcn_s_setprio(1);
    #pragma unroll
    for (int ct = 0; ct < 8; ++ct)
      #pragma unroll
      for (int rt = 0; rt < 4; ++rt)
        acc[rt][ct] = __builtin_amdgcn_mfma_f32_16x16x32_bf16(a0[rt], b0[ct], acc[rt][ct], 0, 0, 0);
    __builtin_amdgcn_s_setprio(0);
    if (k0 < 448) {   // prefetch k0+64 for next iteration
      #pragma unroll
      for (int rt = 0; rt < 4; ++rt) a0[rt] = ldW<BF>(wb, wf, wbase + rt * 8192 + k0 + 64);
      #pragma unroll
      for (int ct = 0; ct < 8; ++ct)
        b0[ct] = *(const short8*)(bbase + ct * 16 * HSTR + (k0 + 64) * 2);
    }
    __builtin_amdgcn_s_setprio(1);
    #pragma unroll
    for (int ct = 0; ct < 8; ++ct)
      #pragma unroll
      for (int rt = 0; rt < 4; ++rt)
        acc[rt][ct] = __builtin_amdgcn_mfma_f32_16x16x32_bf16(a1[rt], b1[ct], acc[rt][ct], 0, 0, 0);
    __builtin_amdgcn_s_setprio(0);
  }
  store_h(acc, bias, hbuf, wave, lane);
}

// ---------------- output layer: 64 neurons x 32 rows per wave, waves 0..3 ----------------
template<bool BF>
__device__ __forceinline__ void final_layer(
    const uint16_t* __restrict__ wb, const float* __restrict__ wf,
    const uint16_t* hbuf, int wave, int lane, f32x4 acc[4][2]) {
  const int l15 = lane & 15, lq = lane >> 4;
  #pragma unroll
  for (int rt = 0; rt < 4; ++rt)
    #pragma unroll
    for (int ct = 0; ct < 2; ++ct) acc[rt][ct] = (f32x4){0.f, 0.f, 0.f, 0.f};
  const int wbase = l15 * 512 + lq * 8;
  #pragma unroll 4
  for (int k0 = 0; k0 < 512; k0 += 32) {
    short8 a[4];
    #pragma unroll
    for (int rt = 0; rt < 4; ++rt) a[rt] = ldW<BF>(wb, wf, wbase + rt * 8192 + k0);
    #pragma unroll
    for (int ct = 0; ct < 2; ++ct) {
      short8 b = ldsB(hbuf, wave * 32 + ct * 16 + l15, lq * 8 + k0);
      #pragma unroll
      for (int rt = 0; rt < 4; ++rt)
        acc[rt][ct] = __builtin_amdgcn_mfma_f32_16x16x32_bf16(a[rt], b, acc[rt][ct], 0, 0, 0);
    }
  }
}

// ---------------- fused coupling kernel: 128 rows/block, 8 waves ----------------
template<bool BF>
__global__ __launch_bounds__(512, 2) void coupling(
    const float* __restrict__ z,
    const float* __restrict__ sWin, const float* __restrict__ sbin,
    const float* __restrict__ sWhid, const float* __restrict__ sbhid,
    const float* __restrict__ sWout, const float* __restrict__ sbout,
    const float* __restrict__ tWin, const float* __restrict__ tbin,
    const float* __restrict__ tWhid, const float* __restrict__ tbhid,
    const float* __restrict__ tWout, const float* __restrict__ tbout,
    const uint16_t* __restrict__ wbf, float* __restrict__ out) {
  extern __shared__ __align__(16) uint16_t h[];     // RPB x HSTR bytes, padded rows
  const int tid = threadIdx.x;
  const int wave = tid >> 6, lane = tid & 63;
  const int l15 = lane & 15, lq = lane >> 4;
  const long rowbase = (long)blockIdx.x * RPB;

  // ---------------- s MLP ----------------
  dense_in<BF>(wbf + OFF_S_WIN, sWin, sbin, z, rowbase, h, wave, lane);
  dense_relu512<BF>(wbf + OFF_S_WHID, sWhid, sbhid, h, wave, lane);
  dense_relu512<BF>(wbf + OFF_S_WHID + 262144, sWhid + 262144, sbhid + 512, h, wave, lane);

  if (wave < 4) {
    f32x4 acc[4][2];
    final_layer<BF>(wbf + OFF_S_WOUT, sWout, h, wave, lane, acc);
    #pragma unroll
    for (int ct = 0; ct < 2; ++ct) {
      const long row = rowbase + wave * 32 + ct * 16 + l15;
      float sum = 0.f;
      #pragma unroll
      for (int rt = 0; rt < 4; ++rt) {
        f32x4 bv = *(const f32x4*)(sbout + rt * 16 + lq * 4);
        f32x4 v = acc[rt][ct] + bv;
        v.x = fminf(fmaxf(v.x, -2.f), 2.f);
        v.y = fminf(fmaxf(v.y, -2.f), 2.f);
        v.z = fminf(fmaxf(v.z, -2.f), 2.f);
        v.w = fminf(fmaxf(v.w, -2.f), 2.f);
        sum += v.x + v.y + v.z + v.w;
        *(f32x4*)(out + row * 128 + 64 + rt * 16 + lq * 4) = v;   // stash log_s
      }
      sum += __shfl_xor(sum, 16, 64);
      sum += __shfl_xor(sum, 32, 64);
      if (lane < 16) out[(long)NROWS * 128 + row] = sum;          // log_det
    }
  } else {
    // waves 4..7: copy z1 passthrough (exact fp32), 128 rows x 64 cols
    #pragma unroll
    for (int i = 0; i < 8; ++i) {
      int v = (wave - 4) * 64 + lane + i * 256;
      int row = v >> 4, kc = (v & 15) * 4;
      *(f32x4*)(out + (rowbase + row) * 128 + kc) =
          *(const f32x4*)(z + (rowbase + row) * 128 + kc);
    }
  }
  __syncthreads();

  // ---------------- t MLP ----------------
  dense_in<BF>(wbf + OFF_T_WIN, tWin, tbin, z, rowbase, h, wave, lane);
  dense_relu512<BF>(wbf + OFF_T_WHID, tWhid, tbhid, h, wave, lane);
  dense_relu512<BF>(wbf + OFF_T_WHID + 262144, tWhid + 262144, tbhid + 512, h, wave, lane);

  if (wave < 4) {
    f32x4 acc[4][2];
    final_layer<BF>(wbf + OFF_T_WOUT, tWout, h, wave, lane, acc);
    #pragma unroll
    for (int ct = 0; ct < 2; ++ct) {
      const long row = rowbase + wave * 32 + ct * 16 + l15;
      #pragma unroll
      for (int rt = 0; rt < 4; ++rt) {
        f32x4 bv = *(const f32x4*)(tbout + rt * 16 + lq * 4);
        f32x4 tv = acc[rt][ct] + bv;
        const long o = row * 128 + 64 + rt * 16 + lq * 4;
        f32x4 ls = *(const f32x4*)(out + o);   // log_s stashed by s-phase (same thread)
        f32x4 z2 = *(const f32x4*)(z + o);     // z2 = z[:,64:] (same offsets)
        f32x4 r;
        r.x = z2.x * __expf(ls.x) + tv.x;
        r.y = z2.y * __expf(ls.y) + tv.y;
        r.z = z2.z * __expf(ls.z) + tv.z;
        r.w = z2.w * __expf(ls.w) + tv.w;
        *(f32x4*)(out + o) = r;
      }
    }
  }
}

extern "C" void kernel_launch(void* const* d_in, const int* in_sizes, int n_in,
                              void* d_out, int out_size, void* d_ws, size_t ws_size,
                              hipStream_t stream) {
  const float* z     = (const float*)d_in[0];
  const float* sWin  = (const float*)d_in[1];
  const float* sbin  = (const float*)d_in[2];
  const float* sWhid = (const float*)d_in[3];
  const float* sbhid = (const float*)d_in[4];
  const float* sWout = (const float*)d_in[5];
  const float* sbout = (const float*)d_in[6];
  const float* tWin  = (const float*)d_in[7];
  const float* tbin  = (const float*)d_in[8];
  const float* tWhid = (const float*)d_in[9];
  const float* tbhid = (const float*)d_in[10];
  const float* tWout = (const float*)d_in[11];
  const float* tbout = (const float*)d_in[12];
  float* out = (float*)d_out;
  const size_t lds_bytes = (size_t)RPB * HSTR;   // 133120 B

  if (ws_size >= (size_t)W_ELEMS * sizeof(uint16_t)) {
    uint16_t* wbf = (uint16_t*)d_ws;
    cvt_weights<<<W_ELEMS / 4 / 256, 256, 0, stream>>>(sWin, sWhid, sWout, tWin, tWhid, tWout, wbf);
    coupling<true><<<NBLK, 512, lds_bytes, stream>>>(z, sWin, sbin, sWhid, sbhid, sWout, sbout,
                                                     tWin, tbin, tWhid, tbhid, tWout, tbout, wbf, out);
  } else {
    coupling<false><<<NBLK, 512, lds_bytes, stream>>>(z, sWin, sbin, sWhid, sbhid, sWout, sbout,
                                                      tWin, tbin, tWhid, tbhid, tWout, tbout,
                                                      (const uint16_t*)d_in[1], out);
  }
}

// Round 5
// 238.528 us; speedup vs baseline: 1.0556x; 1.0556x over previous
//
#include <hip/hip_runtime.h>
#include <stdint.h>

// AffineCoupling: B=65536 rows, DIM=128, D_IN=64, HID=512, 2 extra hidden layers.
// Fused bf16-MFMA. 128 rows/block (512 blocks), 8 waves; each wave owns
// 64 neurons x 128 rows (4x8 16x16x32 frags): 4 A-frag global + 8 B-frag LDS
// reads feed 32 MFMAs per K=32 step.
// LDS h layout is K-MAJOR TILED: granule(ktile=k>>3, row) of 16B at byte
// ktile*2048 + row*16. Perfectly bank-balanced (every bank serves exactly
// 32B per wave b128-read, 16B per wave uint2-write) and LINEAR: all LDS
// accesses are per-lane-base + compile-time immediate (zero in-loop VALU).
// K-loop: A-frags ping-pong one k-step ahead; B-frags rotate one slot ahead
// (+8 VGPRs only -- no spill). setprio(1) wraps each MFMA cluster.
// log_s stashed in out's z2 region between s- and t-MLP (same-thread RAW).

#define NROWS 65536
#define RPB   128
#define NBLK  (NROWS / RPB)

// bf16 weight scratch layout (element offsets in d_ws)
#define OFF_S_WIN   0
#define OFF_S_WHID  32768
#define OFF_S_WOUT  557056
#define OFF_T_WIN   589824
#define OFF_T_WHID  622592
#define OFF_T_WOUT  1146880
#define W_ELEMS     1179648

typedef __attribute__((ext_vector_type(8))) short short8;
typedef __attribute__((ext_vector_type(4))) float f32x4;

__device__ __forceinline__ uint32_t f2bf1(float f) {
  uint32_t u = __float_as_uint(f);
  return (u + 0x7fffu + ((u >> 16) & 1u)) >> 16;   // RNE
}
__device__ __forceinline__ uint32_t pk2bf(float a, float b) {
  return f2bf1(a) | (f2bf1(b) << 16);
}

// ---------------- weight fp32 -> bf16 prologue ----------------
__global__ void cvt_weights(const float* __restrict__ sWin, const float* __restrict__ sWhid,
                            const float* __restrict__ sWout, const float* __restrict__ tWin,
                            const float* __restrict__ tWhid, const float* __restrict__ tWout,
                            uint16_t* __restrict__ wbf) {
  int g = blockIdx.x * blockDim.x + threadIdx.x;
  int e = g * 4;
  if (e >= W_ELEMS) return;
  const float* src; int off;
  if      (e < OFF_S_WHID) { src = sWin;  off = e; }
  else if (e < OFF_S_WOUT) { src = sWhid; off = e - OFF_S_WHID; }
  else if (e < OFF_T_WIN)  { src = sWout; off = e - OFF_S_WOUT; }
  else if (e < OFF_T_WHID) { src = tWin;  off = e - OFF_T_WIN; }
  else if (e < OFF_T_WOUT) { src = tWhid; off = e - OFF_T_WHID; }
  else                     { src = tWout; off = e - OFF_T_WOUT; }
  f32x4 v = *(const f32x4*)(src + off);
  uint2 r; r.x = pk2bf(v.x, v.y); r.y = pk2bf(v.z, v.w);
  *(uint2*)(wbf + e) = r;
}

// ---------------- fragment loaders ----------------
// A-frag (weights, row-major [M][K]): lane l supplies W[m=base+(l&15)][k=(l>>4)*8+j]
template<bool BF>
__device__ __forceinline__ short8 ldW(const uint16_t* __restrict__ wb,
                                      const float* __restrict__ wf, int idx) {
  if (BF) {
    return *(const short8*)(wb + idx);
  } else {  // fallback: convert fp32 weights on the fly
    f32x4 x = *(const f32x4*)(wf + idx);
    f32x4 y = *(const f32x4*)(wf + idx + 4);
    short8 r;
    r[0] = (short)f2bf1(x.x); r[1] = (short)f2bf1(x.y);
    r[2] = (short)f2bf1(x.z); r[3] = (short)f2bf1(x.w);
    r[4] = (short)f2bf1(y.x); r[5] = (short)f2bf1(y.y);
    r[6] = (short)f2bf1(y.z); r[7] = (short)f2bf1(y.w);
    return r;
  }
}

// ---------------- epilogue: bias + relu + pack + k-major LDS store ----------------
// h[row][n] lives at byte (n>>3)*2048 + row*16 + (n&7)*2.
__device__ __forceinline__ void store_h(f32x4 acc[4][8], const float* __restrict__ bias,
                                        uint16_t* hdst, int wave, int lane) {
  const int l15 = lane & 15, lq = lane >> 4;
  __syncthreads();   // all waves done READING h (h is read+written in place)
  char* wp = (char*)hdst + wave * 16384 + (lq >> 1) * 2048 + (lq & 1) * 8 + l15 * 16;
  #pragma unroll
  for (int rt = 0; rt < 4; ++rt) {
    const int n0 = wave * 64 + rt * 16 + lq * 4;
    f32x4 bv = *(const f32x4*)(bias + n0);
    #pragma unroll
    for (int ct = 0; ct < 8; ++ct) {
      f32x4 v = acc[rt][ct] + bv;
      uint2 p;
      p.x = pk2bf(fmaxf(v.x, 0.f), fmaxf(v.y, 0.f));
      p.y = pk2bf(fmaxf(v.z, 0.f), fmaxf(v.w, 0.f));
      *(uint2*)(wp + rt * 4096 + ct * 256) = p;
    }
  }
  __syncthreads();
}

// ---------------- layer 1: h = relu(W @ z1^T + b), K=64, B built from global z ----------------
template<bool BF>
__device__ __forceinline__ void dense_in(
    const uint16_t* __restrict__ wb, const float* __restrict__ wf,
    const float* __restrict__ bias, const float* __restrict__ z, long rowbase,
    uint16_t* hdst, int wave, int lane) {
  const int l15 = lane & 15, lq = lane >> 4;
  f32x4 acc[4][8];
  #pragma unroll
  for (int rt = 0; rt < 4; ++rt)
    #pragma unroll
    for (int ct = 0; ct < 8; ++ct) acc[rt][ct] = (f32x4){0.f, 0.f, 0.f, 0.f};
  const int wbase = (wave * 64 + l15) * 64 + lq * 8;
  #pragma unroll
  for (int k0 = 0; k0 < 64; k0 += 32) {
    short8 a[4];
    #pragma unroll
    for (int rt = 0; rt < 4; ++rt) a[rt] = ldW<BF>(wb, wf, wbase + rt * 1024 + k0);
    #pragma unroll
    for (int ct = 0; ct < 8; ++ct) {
      const float* zp = z + (rowbase + ct * 16 + l15) * 128 + lq * 8 + k0;
      f32x4 u = *(const f32x4*)zp;
      f32x4 v = *(const f32x4*)(zp + 4);
      short8 b;
      b[0] = (short)f2bf1(u.x); b[1] = (short)f2bf1(u.y);
      b[2] = (short)f2bf1(u.z); b[3] = (short)f2bf1(u.w);
      b[4] = (short)f2bf1(v.x); b[5] = (short)f2bf1(v.y);
      b[6] = (short)f2bf1(v.z); b[7] = (short)f2bf1(v.w);
      #pragma unroll
      for (int rt = 0; rt < 4; ++rt)
        acc[rt][ct] = __builtin_amdgcn_mfma_f32_16x16x32_bf16(a[rt], b, acc[rt][ct], 0, 0, 0);
    }
  }
  store_h(acc, bias, hdst, wave, lane);
}

// ---------------- hidden layer: h = relu(W @ h^T + b), K=512 ----------------
// A ping-pong (one k-step ahead) + B one-slot rotation. All LDS reads are
// per-lane base + immediate; base advances once per 4 k-steps.
template<bool BF>
__device__ __forceinline__ void dense_relu512(
    const uint16_t* __restrict__ wb, const float* __restrict__ wf,
    const float* __restrict__ bias, uint16_t* hbuf, int wave, int lane) {
  const int l15 = lane & 15, lq = lane >> 4;
  f32x4 acc[4][8];
  #pragma unroll
  for (int rt = 0; rt < 4; ++rt)
    #pragma unroll
    for (int ct = 0; ct < 8; ++ct) acc[rt][ct] = (f32x4){0.f, 0.f, 0.f, 0.f};
  const int wbase = (wave * 64 + l15) * 512 + lq * 8;
  const char* bb = (const char*)hbuf + l15 * 16 + lq * 2048;

  short8 a[2][4];
  #pragma unroll
  for (int rt = 0; rt < 4; ++rt) a[0][rt] = ldW<BF>(wb, wf, wbase + rt * 8192);
  short8 bcur = *(const short8*)bb;   // slot (k0=0, ct=0)

  #pragma unroll 1
  for (int ko = 0; ko < 512; ko += 128) {
    #pragma unroll
    for (int kk = 0; kk < 4; ++kk) {
      // prefetch next k-step's A fragments (clamped re-read at the very end)
      int kn = ko + kk * 32 + 32;
      if (kn > 480) kn = 480;
      #pragma unroll
      for (int rt = 0; rt < 4; ++rt)
        a[(kk + 1) & 1][rt] = ldW<BF>(wb, wf, wbase + rt * 8192 + kn);
      __builtin_amdgcn_s_setprio(1);
      #pragma unroll
      for (int ct = 0; ct < 8; ++ct) {
        // read next slot's B (ct+1, or ct=0 of next k-step) one ahead
        const int noff = (ct < 7) ? (kk * 8192 + (ct + 1) * 256) : ((kk + 1) * 8192);
        short8 bn = *(const short8*)(bb + noff);
        #pragma unroll
        for (int rt = 0; rt < 4; ++rt)
          acc[rt][ct] = __builtin_amdgcn_mfma_f32_16x16x32_bf16(a[kk & 1][rt], bcur, acc[rt][ct], 0, 0, 0);
        bcur = bn;
      }
      __builtin_amdgcn_s_setprio(0);
    }
    bb += 32768;
  }
  store_h(acc, bias, hbuf, wave, lane);
}

// ---------------- output layer: 64 neurons x 32 rows per wave, waves 0..3 ----------------
template<bool BF>
__device__ __forceinline__ void final_layer(
    const uint16_t* __restrict__ wb, const float* __restrict__ wf,
    const uint16_t* hbuf, int wave, int lane, f32x4 acc[4][2]) {
  const int l15 = lane & 15, lq = lane >> 4;
  #pragma unroll
  for (int rt = 0; rt < 4; ++rt)
    #pragma unroll
    for (int ct = 0; ct < 2; ++ct) acc[rt][ct] = (f32x4){0.f, 0.f, 0.f, 0.f};
  const int wbase = l15 * 512 + lq * 8;
  const char* fb = (const char*)hbuf + (wave * 32 + l15) * 16 + lq * 2048;
  #pragma unroll 1
  for (int ko = 0; ko < 512; ko += 128) {
    #pragma unroll
    for (int kk = 0; kk < 4; ++kk) {
      short8 a[4];
      #pragma unroll
      for (int rt = 0; rt < 4; ++rt)
        a[rt] = ldW<BF>(wb, wf, wbase + rt * 8192 + ko + kk * 32);
      #pragma unroll
      for (int ct = 0; ct < 2; ++ct) {
        short8 b = *(const short8*)(fb + kk * 8192 + ct * 256);
        #pragma unroll
        for (int rt = 0; rt < 4; ++rt)
          acc[rt][ct] = __builtin_amdgcn_mfma_f32_16x16x32_bf16(a[rt], b, acc[rt][ct], 0, 0, 0);
      }
    }
    fb += 32768;
  }
}

// ---------------- fused coupling kernel: 128 rows/block, 8 waves ----------------
template<bool BF>
__global__ __launch_bounds__(512, 2) void coupling(
    const float* __restrict__ z,
    const float* __restrict__ sWin, const float* __restrict__ sbin,
    const float* __restrict__ sWhid, const float* __restrict__ sbhid,
    const float* __restrict__ sWout, const float* __restrict__ sbout,
    const float* __restrict__ tWin, const float* __restrict__ tbin,
    const float* __restrict__ tWhid, const float* __restrict__ tbhid,
    const float* __restrict__ tWout, const float* __restrict__ tbout,
    const uint16_t* __restrict__ wbf, float* __restrict__ out) {
  extern __shared__ __align__(16) uint16_t h[];     // 128 KiB k-major + 8 KiB guard
  const int tid = threadIdx.x;
  const int wave = tid >> 6, lane = tid & 63;
  const int l15 = lane & 15, lq = lane >> 4;
  const long rowbase = (long)blockIdx.x * RPB;

  // ---------------- s MLP ----------------
  dense_in<BF>(wbf + OFF_S_WIN, sWin, sbin, z, rowbase, h, wave, lane);
  dense_relu512<BF>(wbf + OFF_S_WHID, sWhid, sbhid, h, wave, lane);
  dense_relu512<BF>(wbf + OFF_S_WHID + 262144, sWhid + 262144, sbhid + 512, h, wave, lane);

  if (wave < 4) {
    f32x4 acc[4][2];
    final_layer<BF>(wbf + OFF_S_WOUT, sWout, h, wave, lane, acc);
    #pragma unroll
    for (int ct = 0; ct < 2; ++ct) {
      const long row = rowbase + wave * 32 + ct * 16 + l15;
      float sum = 0.f;
      #pragma unroll
      for (int rt = 0; rt < 4; ++rt) {
        f32x4 bv = *(const f32x4*)(sbout + rt * 16 + lq * 4);
        f32x4 v = acc[rt][ct] + bv;
        v.x = fminf(fmaxf(v.x, -2.f), 2.f);
        v.y = fminf(fmaxf(v.y, -2.f), 2.f);
        v.z = fminf(fmaxf(v.z, -2.f), 2.f);
        v.w = fminf(fmaxf(v.w, -2.f), 2.f);
        sum += v.x + v.y + v.z + v.w;
        *(f32x4*)(out + row * 128 + 64 + rt * 16 + lq * 4) = v;   // stash log_s
      }
      sum += __shfl_xor(sum, 16, 64);
      sum += __shfl_xor(sum, 32, 64);
      if (lane < 16) out[(long)NROWS * 128 + row] = sum;          // log_det
    }
  } else {
    // waves 4..7: copy z1 passthrough (exact fp32), 128 rows x 64 cols
    #pragma unroll
    for (int i = 0; i < 8; ++i) {
      int v = (wave - 4) * 64 + lane + i * 256;
      int row = v >> 4, kc = (v & 15) * 4;
      *(f32x4*)(out + (rowbase + row) * 128 + kc) =
          *(const f32x4*)(z + (rowbase + row) * 128 + kc);
    }
  }
  __syncthreads();

  // ---------------- t MLP ----------------
  dense_in<BF>(wbf + OFF_T_WIN, tWin, tbin, z, rowbase, h, wave, lane);
  dense_relu512<BF>(wbf + OFF_T_WHID, tWhid, tbhid, h, wave, lane);
  dense_relu512<BF>(wbf + OFF_T_WHID + 262144, tWhid + 262144, tbhid + 512, h, wave, lane);

  if (wave < 4) {
    f32x4 acc[4][2];
    final_layer<BF>(wbf + OFF_T_WOUT, tWout, h, wave, lane, acc);
    #pragma unroll
    for (int ct = 0; ct < 2; ++ct) {
      const long row = rowbase + wave * 32 + ct * 16 + l15;
      #pragma unroll
      for (int rt = 0; rt < 4; ++rt) {
        f32x4 bv = *(const f32x4*)(tbout + rt * 16 + lq * 4);
        f32x4 tv = acc[rt][ct] + bv;
        const long o = row * 128 + 64 + rt * 16 + lq * 4;
        f32x4 ls = *(const f32x4*)(out + o);   // log_s stashed by s-phase (same thread)
        f32x4 z2 = *(const f32x4*)(z + o);     // z2 = z[:,64:] (same offsets)
        f32x4 r;
        r.x = z2.x * __expf(ls.x) + tv.x;
        r.y = z2.y * __expf(ls.y) + tv.y;
        r.z = z2.z * __expf(ls.z) + tv.z;
        r.w = z2.w * __expf(ls.w) + tv.w;
        *(f32x4*)(out + o) = r;
      }
    }
  }
}

extern "C" void kernel_launch(void* const* d_in, const int* in_sizes, int n_in,
                              void* d_out, int out_size, void* d_ws, size_t ws_size,
                              hipStream_t stream) {
  const float* z     = (const float*)d_in[0];
  const float* sWin  = (const float*)d_in[1];
  const float* sbin  = (const float*)d_in[2];
  const float* sWhid = (const float*)d_in[3];
  const float* sbhid = (const float*)d_in[4];
  const float* sWout = (const float*)d_in[5];
  const float* sbout = (const float*)d_in[6];
  const float* tWin  = (const float*)d_in[7];
  const float* tbin  = (const float*)d_in[8];
  const float* tWhid = (const float*)d_in[9];
  const float* tbhid = (const float*)d_in[10];
  const float* tWout = (const float*)d_in[11];
  const float* tbout = (const float*)d_in[12];
  float* out = (float*)d_out;
  const size_t lds_bytes = 139264;   // 128 KiB h (k-major) + 8 KiB rotation guard

  if (ws_size >= (size_t)W_ELEMS * sizeof(uint16_t)) {
    uint16_t* wbf = (uint16_t*)d_ws;
    cvt_weights<<<W_ELEMS / 4 / 256, 256, 0, stream>>>(sWin, sWhid, sWout, tWin, tWhid, tWout, wbf);
    coupling<true><<<NBLK, 512, lds_bytes, stream>>>(z, sWin, sbin, sWhid, sbhid, sWout, sbout,
                                                     tWin, tbin, tWhid, tbhid, tWout, tbout, wbf, out);
  } else {
    coupling<false><<<NBLK, 512, lds_bytes, stream>>>(z, sWin, sbin, sWhid, sbhid, sWout, sbout,
                                                      tWin, tbin, tWhid, tbhid, tWout, tbout,
                                                      (const uint16_t*)d_in[1], out);
  }
}